// Round 10
// baseline (191.162 us; speedup 1.0000x reference)
//
#include <hip/hip_runtime.h>
#include <hip/hip_cooperative_groups.h>

namespace cg = cooperative_groups;

#define Hh 64
#define Ww 64
#define Cc 128   // FEAT_DIM
#define ND 64    // NODE_DIM
#define BSz 32
#define TOPK 4096
#define HW (Hh * Ww)
#define NPX (BSz * HW)      // 131072 pixels == sample count

typedef short bf16x8 __attribute__((ext_vector_type(8)));
typedef unsigned short u16x8 __attribute__((ext_vector_type(8)));
typedef unsigned short u16x4 __attribute__((ext_vector_type(4)));
typedef float f32x4 __attribute__((ext_vector_type(4)));

static __device__ __forceinline__ unsigned short f2bf(float f) {
    unsigned int u = __builtin_bit_cast(unsigned int, f);
    u += 0x7fffu + ((u >> 16) & 1u);   // RNE (finite data)
    return (unsigned short)(u >> 16);
}
static __device__ __forceinline__ float bf2f(unsigned short s) {
    unsigned int u = ((unsigned int)s) << 16;
    return __builtin_bit_cast(float, u);
}

// U in "position space": channel c at position p = pi(c) = (c&15)*4 + (c>>4).
// GEMM1 C-stores become lane-contiguous; GEMM2 relabels the k-axis (exact).

// ---------------- shared device helpers (weight staging) ----------------
static __device__ __forceinline__ void stage_w1(const float* __restrict__ W1,
                                                unsigned short* w1s, int t) {
#pragma unroll
    for (int k = 0; k < 32; ++k) {
        int i = t + 256 * k;                       // 8192, coalesced read
        int c = i >> 6, n = i & 63;
        int kk = c >> 5, gg = (c >> 3) & 3, j = c & 7;
        int nt = n >> 4, mr2 = n & 15;
        w1s[((nt * 4 + kk) * 64 + gg * 16 + mr2) * 8 + j] = f2bf(W1[i]);
    }
}
static __device__ __forceinline__ void stage_w2(const float* __restrict__ W2,
                                                unsigned short* w2s, int t) {
#pragma unroll
    for (int k = 0; k < 16; ++k) {
        int i = t + 256 * k;                       // 4096, coalesced read
        int kch = i >> 6, n = i & 63;
        int p = ((kch & 15) << 2) | (kch >> 4);    // pi(k)
        int kk = p >> 5, gg = (p >> 3) & 3, e = p & 7;
        int nt = n >> 4, mr2 = n & 15;
        w2s[((nt * 2 + kk) * 64 + gg * 16 + mr2) * 8 + e] = f2bf(W2[i]);
    }
}

// ---------------- phase A body: 128 pixels starting at p0w (per wave) ----------------
static __device__ __forceinline__ void phaseA(const float* __restrict__ fm,
                                              const unsigned short* w1s,
                                              unsigned short* __restrict__ U,
                                              int p0, int g, int mr, int lane) {
    const int b   = p0 >> 12;
    const int pin = p0 & 4095;
    const float* fb = fm + (size_t)b * (Cc * HW);

    bf16x8 aF[2][4];
#pragma unroll
    for (int half = 0; half < 2; ++half) {
        const int px = pin + half * 16 + mr;
#pragma unroll
        for (int kk = 0; kk < 4; ++kk) {
            float v[8];
#pragma unroll
            for (int j = 0; j < 8; ++j)
                v[j] = fb[(size_t)(kk * 32 + 8 * g + j) * HW + px];
            u16x8 o;
#pragma unroll
            for (int j = 0; j < 8; ++j) o[j] = f2bf(v[j]);
            aF[half][kk] = __builtin_bit_cast(bf16x8, o);
        }
    }

    f32x4 acc[2][4];
#pragma unroll
    for (int mt = 0; mt < 2; ++mt)
#pragma unroll
        for (int nt = 0; nt < 4; ++nt) acc[mt][nt] = (f32x4){0.f, 0.f, 0.f, 0.f};
#pragma unroll
    for (int kk = 0; kk < 4; ++kk)
#pragma unroll
        for (int nt = 0; nt < 4; ++nt) {
            bf16x8 bF = *(const bf16x8*)&w1s[((nt * 4 + kk) * 64 + lane) * 8];
            acc[0][nt] = __builtin_amdgcn_mfma_f32_16x16x32_bf16(aF[0][kk], bF, acc[0][nt], 0, 0, 0);
            acc[1][nt] = __builtin_amdgcn_mfma_f32_16x16x32_bf16(aF[1][kk], bF, acc[1][nt], 0, 0, 0);
        }

#pragma unroll
    for (int mt = 0; mt < 2; ++mt)
#pragma unroll
        for (int r = 0; r < 4; ++r) {
            const int row = p0 + mt * 16 + 4 * g + r;
            u16x4 v4;
#pragma unroll
            for (int nt = 0; nt < 4; ++nt) v4[nt] = f2bf(acc[mt][nt][r]);
            *(u16x4*)&U[(size_t)row * ND + mr * 4] = v4;
        }
}

// ---------------- phase B body: 32 samples starting at m0 (per wave) ----------------
static __device__ __forceinline__ void phaseB(const unsigned short* __restrict__ U,
                                              const float* __restrict__ pc,
                                              const unsigned short* w2s,
                                              const float* b1s, const float* b2s,
                                              float* __restrict__ out,
                                              int m0, int g, int mr, int lane) {
    const int bb = m0 >> 12;
    const unsigned short* Ub = U + (size_t)bb * (HW * ND) + 8 * g;

    float w00[2], w01[2], w10[2], w11[2];
    const u16x8* q[2][4];
#pragma unroll
    for (int h = 0; h < 2; ++h) {
        const int sm = m0 + h * 16 + mr;
        const float y = pc[2 * (size_t)sm + 0];
        const float x = pc[2 * (size_t)sm + 1];
        const float yf = floorf(y), xf = floorf(x);
        const float ty = y - yf, tx = x - xf;
        int y0 = min(max((int)yf, 0), Hh - 1);
        int x0 = min(max((int)xf, 0), Ww - 1);
        int y1 = min(y0 + 1, Hh - 1);
        int x1 = min(x0 + 1, Ww - 1);
        w00[h] = (1.f - ty) * (1.f - tx); w01[h] = (1.f - ty) * tx;
        w10[h] = ty * (1.f - tx);         w11[h] = ty * tx;
        q[h][0] = (const u16x8*)(Ub + (y0 * Ww + x0) * ND);
        q[h][1] = (const u16x8*)(Ub + (y0 * Ww + x1) * ND);
        q[h][2] = (const u16x8*)(Ub + (y1 * Ww + x0) * ND);
        q[h][3] = (const u16x8*)(Ub + (y1 * Ww + x1) * ND);
    }
    u16x8 rg[2][8];
#pragma unroll
    for (int h = 0; h < 2; ++h)
#pragma unroll
        for (int c2 = 0; c2 < 4; ++c2) {
            rg[h][c2 * 2 + 0] = q[h][c2][0];
            rg[h][c2 * 2 + 1] = q[h][c2][4];
        }

    bf16x8 aF[2][2];
#pragma unroll
    for (int h = 0; h < 2; ++h)
#pragma unroll
        for (int kk = 0; kk < 2; ++kk) {
            f32x4 bA = *(const f32x4*)&b1s[kk * 32 + 8 * g];
            f32x4 bB = *(const f32x4*)&b1s[kk * 32 + 8 * g + 4];
            u16x8 o;
#pragma unroll
            for (int j = 0; j < 8; ++j) {
                float v = w00[h] * bf2f(rg[h][0 + kk][j]) + w01[h] * bf2f(rg[h][2 + kk][j])
                        + w10[h] * bf2f(rg[h][4 + kk][j]) + w11[h] * bf2f(rg[h][6 + kk][j]);
                float bv = (j < 4) ? bA[j & 3] : bB[j & 3];
                o[j] = f2bf(fmaxf(v + bv, 0.f));
            }
            aF[h][kk] = __builtin_bit_cast(bf16x8, o);
        }

    f32x4 acc2[2][4];
#pragma unroll
    for (int mt = 0; mt < 2; ++mt)
#pragma unroll
        for (int nt = 0; nt < 4; ++nt) {
            const float bc = b2s[nt * 16 + mr];
            acc2[mt][nt] = (f32x4){bc, bc, bc, bc};
        }
#pragma unroll
    for (int kk = 0; kk < 2; ++kk)
#pragma unroll
        for (int nt = 0; nt < 4; ++nt) {
            bf16x8 bF = *(const bf16x8*)&w2s[((nt * 2 + kk) * 64 + lane) * 8];
            acc2[0][nt] = __builtin_amdgcn_mfma_f32_16x16x32_bf16(aF[0][kk], bF, acc2[0][nt], 0, 0, 0);
            acc2[1][nt] = __builtin_amdgcn_mfma_f32_16x16x32_bf16(aF[1][kk], bF, acc2[1][nt], 0, 0, 0);
        }

#pragma unroll
    for (int mt = 0; mt < 2; ++mt) {
        f32x4 ss = (f32x4){0.f, 0.f, 0.f, 0.f};
#pragma unroll
        for (int nt = 0; nt < 4; ++nt)
#pragma unroll
            for (int r = 0; r < 4; ++r) ss[r] += acc2[mt][nt][r] * acc2[mt][nt][r];
#pragma unroll
        for (int off = 1; off <= 8; off <<= 1) {
#pragma unroll
            for (int r = 0; r < 4; ++r) ss[r] += __shfl_xor(ss[r], off);
        }
#pragma unroll
        for (int r = 0; r < 4; ++r) {
            const float inv = 1.f / fmaxf(sqrtf(ss[r]), 1e-12f);
            const size_t ob = (size_t)(m0 + mt * 16 + 4 * g + r) * ND;
#pragma unroll
            for (int nt = 0; nt < 4; ++nt)
                out[ob + nt * 16 + mr] = acc2[mt][nt][r] * inv;
        }
    }
}

// ---------------- merged cooperative kernel: 512 blocks x 256 ----------------
__global__ __launch_bounds__(256, 4)
void k_merged(const float* __restrict__ fm,  const float* __restrict__ pc,
              const float* __restrict__ W1,  const float* __restrict__ b1,
              const float* __restrict__ W2,  const float* __restrict__ b2,
              unsigned short* __restrict__ U, float* __restrict__ out) {
    __shared__ __align__(16) unsigned short w1s[8192];
    __shared__ __align__(16) unsigned short w2s[4096];
    __shared__ __align__(16) float b1s[64];
    __shared__ __align__(16) float b2s[64];

    const int t = threadIdx.x;
    stage_w1(W1, w1s, t);
    stage_w2(W2, w2s, t);
    if (t < 64) { b1s[t] = b1[((t & 3) << 4) | (t >> 2)]; b2s[t] = b2[t]; }
    __syncthreads();

    const int bid = blockIdx.x;
    const int swz = (bid & 7) * 64 + (bid >> 3);   // bijective on 512
    const int lane = t & 63, wv = t >> 6;
    const int g = lane >> 4, mr = lane & 15;

#pragma unroll
    for (int c2 = 0; c2 < 2; ++c2)
        phaseA(fm, w1s, U, swz * 256 + c2 * 128 + wv * 32, g, mr, lane);

    __threadfence();
    cg::this_grid().sync();

#pragma unroll
    for (int c2 = 0; c2 < 2; ++c2)
        phaseB(U, pc, w2s, b1s, b2s, out, swz * 256 + c2 * 128 + wv * 32, g, mr, lane);
}

// ---------------- fallback two-kernel path (R8, known-good) ----------------
__global__ __launch_bounds__(256) void k_mlp1(const float* __restrict__ fm,
                                              const float* __restrict__ W1,
                                              unsigned short* __restrict__ U) {
    __shared__ __align__(16) unsigned short w1s[8192];
    const int t = threadIdx.x;
    stage_w1(W1, w1s, t);
    __syncthreads();
    const int bid = blockIdx.x;
    const int swz = (bid & 7) * 128 + (bid >> 3);  // bijective on 1024
    const int lane = t & 63, wv = t >> 6;
    phaseA(fm, w1s, U, swz * 128 + wv * 32, lane >> 4, lane & 15, lane);
}

__global__ __launch_bounds__(256) void k_fused2(const unsigned short* __restrict__ U,
                                                const float* __restrict__ pc,
                                                const float* __restrict__ W2,
                                                const float* __restrict__ b1,
                                                const float* __restrict__ b2,
                                                float* __restrict__ out) {
    __shared__ __align__(16) unsigned short w2s[4096];
    __shared__ __align__(16) float b1s[64];
    __shared__ __align__(16) float b2s[64];
    const int t = threadIdx.x;
    stage_w2(W2, w2s, t);
    if (t < 64) { b1s[t] = b1[((t & 3) << 4) | (t >> 2)]; b2s[t] = b2[t]; }
    __syncthreads();
    const int bid = blockIdx.x;
    const int swz = (bid & 7) * 128 + (bid >> 3);  // bijective on 1024
    const int lane = t & 63, wv = t >> 6;
    phaseB(U, pc, w2s, b1s, b2s, out, swz * 128 + wv * 32, lane >> 4, lane & 15, lane);
}

extern "C" void kernel_launch(void* const* d_in, const int* in_sizes, int n_in,
                              void* d_out, int out_size, void* d_ws, size_t ws_size,
                              hipStream_t stream) {
    const float* fm = (const float*)d_in[0];
    const float* pc = (const float*)d_in[1];
    const float* W1 = (const float*)d_in[2];
    const float* b1 = (const float*)d_in[3];
    const float* W2 = (const float*)d_in[4];
    const float* b2 = (const float*)d_in[5];
    float* out = (float*)d_out;
    unsigned short* U = (unsigned short*)d_ws;     // 131072 x 64 bf16 = 16 MB

    // Deterministic host-side feasibility check (pure queries, capture-safe).
    int dev = 0, coop = 0, ncu = 0, maxb = 0;
    hipGetDevice(&dev);
    hipDeviceGetAttribute(&coop, hipDeviceAttributeCooperativeLaunch, dev);
    hipDeviceGetAttribute(&ncu, hipDeviceAttributeMultiprocessorCount, dev);
    hipOccupancyMaxActiveBlocksPerMultiprocessor(&maxb, (const void*)k_merged, 256, 0);

    if (coop && (long)maxb * ncu >= 512) {
        void* args[] = {(void*)&fm, (void*)&pc, (void*)&W1, (void*)&b1,
                        (void*)&W2, (void*)&b2, (void*)&U, (void*)&out};
        hipError_t e = hipLaunchCooperativeKernel((const void*)k_merged, dim3(512),
                                                  dim3(256), args, 0, stream);
        if (e == hipSuccess) return;
    }
    // Fallback: known-good two-kernel path.
    k_mlp1<<<NPX / 128, 256, 0, stream>>>(fm, W1, U);
    k_fused2<<<NPX / 128, 256, 0, stream>>>(U, pc, W2, b1, b2, out);
}

// Round 11
// 34.813 us; speedup vs baseline: 5.4911x; 5.4911x over previous
//
#include <hip/hip_runtime.h>

#define Hh 64
#define Ww 64
#define Cc 128   // FEAT_DIM
#define ND 64    // NODE_DIM
#define BSz 32
#define TOPK 4096
#define HW (Hh * Ww)
#define NPX (BSz * HW)      // 131072 pixels == sample count

typedef short bf16x8 __attribute__((ext_vector_type(8)));
typedef unsigned short u16x8 __attribute__((ext_vector_type(8)));
typedef unsigned short u16x4 __attribute__((ext_vector_type(4)));
typedef float f32x4 __attribute__((ext_vector_type(4)));

static __device__ __forceinline__ unsigned short f2bf(float f) {
    unsigned int u = __builtin_bit_cast(unsigned int, f);
    u += 0x7fffu + ((u >> 16) & 1u);   // RNE (finite data)
    return (unsigned short)(u >> 16);
}
static __device__ __forceinline__ float bf2f(unsigned short s) {
    unsigned int u = ((unsigned int)s) << 16;
    return __builtin_bit_cast(float, u);
}

// U in "position space": channel c at position p = pi(c) = (c&15)*4 + (c>>4).
// GEMM1 C-stores become lane-contiguous; GEMM2 relabels the k-axis (exact).

// ---------------- weight staging (coalesced read -> LDS scatter) ----------------
static __device__ __forceinline__ void stage_w1(const float* __restrict__ W1,
                                                unsigned short* w1s, int t) {
#pragma unroll
    for (int k = 0; k < 32; ++k) {
        int i = t + 256 * k;                       // 8192, coalesced read
        int c = i >> 6, n = i & 63;
        int kk = c >> 5, gg = (c >> 3) & 3, j = c & 7;
        int nt = n >> 4, mr2 = n & 15;
        w1s[((nt * 4 + kk) * 64 + gg * 16 + mr2) * 8 + j] = f2bf(W1[i]);
    }
}
static __device__ __forceinline__ void stage_w2(const float* __restrict__ W2,
                                                unsigned short* w2s, int t) {
#pragma unroll
    for (int k = 0; k < 16; ++k) {
        int i = t + 256 * k;                       // 4096, coalesced read
        int kch = i >> 6, n = i & 63;
        int p = ((kch & 15) << 2) | (kch >> 4);    // pi(k)
        int kk = p >> 5, gg = (p >> 3) & 3, e = p & 7;
        int nt = n >> 4, mr2 = n & 15;
        w2s[((nt * 2 + kk) * 64 + gg * 16 + mr2) * 8 + e] = f2bf(W2[i]);
    }
}

// ---------- k_mlp1: U[px][p] = pi(fm @ W1), dense, from NCHW fp32 ----------
// Row-pair relabel: fragment-row mr of MFMA#half holds pixel pin + 2*mr + half
// -> fm loads are float2 (full 128 B lines per channel segment, half the
// load instructions). Output rows tracked at the U store (exact relabel).
__global__ __launch_bounds__(256) void k_mlp1(const float* __restrict__ fm,
                                              const float* __restrict__ W1,
                                              unsigned short* __restrict__ U) {
    __shared__ __align__(16) unsigned short w1s[8192];   // 16 KB, B-frag order
    const int t = threadIdx.x;
    stage_w1(W1, w1s, t);
    __syncthreads();

    const int bid = blockIdx.x;
    const int swz = (bid & 7) * 128 + (bid >> 3);  // bijective on 1024
    const int lane = t & 63, wv = t >> 6;
    const int g = lane >> 4, mr = lane & 15;
    const int p0  = swz * 128 + wv * 32;           // wave's first global pixel
    const int b   = p0 >> 12;                      // batch (block stays in one batch)
    const int pin = p0 & 4095;
    const float* fb = fm + (size_t)b * (Cc * HW);

    bf16x8 aF[2][4];
#pragma unroll
    for (int kk = 0; kk < 4; ++kk) {
        u16x8 o0, o1;
#pragma unroll
        for (int j = 0; j < 8; ++j) {
            float2 v2 = *(const float2*)&fb[(size_t)(kk * 32 + 8 * g + j) * HW + pin + 2 * mr];
            o0[j] = f2bf(v2.x);
            o1[j] = f2bf(v2.y);
        }
        aF[0][kk] = __builtin_bit_cast(bf16x8, o0);
        aF[1][kk] = __builtin_bit_cast(bf16x8, o1);
    }

    f32x4 acc[2][4];
#pragma unroll
    for (int hh = 0; hh < 2; ++hh)
#pragma unroll
        for (int nt = 0; nt < 4; ++nt) acc[hh][nt] = (f32x4){0.f, 0.f, 0.f, 0.f};
#pragma unroll
    for (int kk = 0; kk < 4; ++kk)
#pragma unroll
        for (int nt = 0; nt < 4; ++nt) {
            bf16x8 bF = *(const bf16x8*)&w1s[((nt * 4 + kk) * 64 + lane) * 8];
            acc[0][nt] = __builtin_amdgcn_mfma_f32_16x16x32_bf16(aF[0][kk], bF, acc[0][nt], 0, 0, 0);
            acc[1][nt] = __builtin_amdgcn_mfma_f32_16x16x32_bf16(aF[1][kk], bF, acc[1][nt], 0, 0, 0);
        }

    // store U in position space: MFMA#half fragment-row (4g+r) is pixel
    // p0 + 2*(4g+r) + half; 16 mr-lanes cover 128 B contiguous per row.
#pragma unroll
    for (int hh = 0; hh < 2; ++hh)
#pragma unroll
        for (int r = 0; r < 4; ++r) {
            const int row = p0 + 2 * (4 * g + r) + hh;
            u16x4 v4;
#pragma unroll
            for (int nt = 0; nt < 4; ++nt) v4[nt] = f2bf(acc[hh][nt][r]);
            *(u16x4*)&U[(size_t)row * ND + mr * 4] = v4;
        }
}

// ---------- k_fused2: gather U + interp + b1/relu -> GEMM2 -> normalize ----------
// 1024 blocks x 256 thr; 128 samples/block, 32/wave (2/lane -> 16 gather loads
// in flight). pc loads issued BEFORE weight staging (latency hidden).
__global__ __launch_bounds__(256) void k_fused2(const unsigned short* __restrict__ U,
                                                const float* __restrict__ pc,
                                                const float* __restrict__ W2,
                                                const float* __restrict__ b1,
                                                const float* __restrict__ b2,
                                                float* __restrict__ out) {
    __shared__ __align__(16) unsigned short w2s[4096];   // 8 KB, B-frag order
    __shared__ __align__(16) float b1s[64];              // position-permuted
    __shared__ __align__(16) float b2s[64];
    const int t = threadIdx.x;
    const int bid = blockIdx.x;
    const int swz = (bid & 7) * 128 + (bid >> 3);  // bijective on 1024
    const int lane = t & 63, wv = t >> 6;
    const int g = lane >> 4, mr = lane & 15;
    const int m0 = swz * 128 + wv * 32;            // wave's 32 samples

    // prefetch coords first (hide under staging + barrier)
    float2 pcv[2];
#pragma unroll
    for (int h = 0; h < 2; ++h)
        pcv[h] = *(const float2*)&pc[2 * (size_t)(m0 + h * 16 + mr)];

    stage_w2(W2, w2s, t);
    if (t < 64) { b1s[t] = b1[((t & 3) << 4) | (t >> 2)]; b2s[t] = b2[t]; }
    __syncthreads();

    const int bb = m0 >> 12;                       // batch (XCD-local U)
    const unsigned short* Ub = U + (size_t)bb * (HW * ND) + 8 * g;

    float w00[2], w01[2], w10[2], w11[2];
    const u16x8* q[2][4];
#pragma unroll
    for (int h = 0; h < 2; ++h) {
        const float y = pcv[h].x;
        const float x = pcv[h].y;
        const float yf = floorf(y), xf = floorf(x);
        const float ty = y - yf, tx = x - xf;
        int y0 = min(max((int)yf, 0), Hh - 1);
        int x0 = min(max((int)xf, 0), Ww - 1);
        int y1 = min(y0 + 1, Hh - 1);
        int x1 = min(x0 + 1, Ww - 1);
        w00[h] = (1.f - ty) * (1.f - tx); w01[h] = (1.f - ty) * tx;
        w10[h] = ty * (1.f - tx);         w11[h] = ty * tx;
        q[h][0] = (const u16x8*)(Ub + (y0 * Ww + x0) * ND);
        q[h][1] = (const u16x8*)(Ub + (y0 * Ww + x1) * ND);
        q[h][2] = (const u16x8*)(Ub + (y1 * Ww + x0) * ND);
        q[h][3] = (const u16x8*)(Ub + (y1 * Ww + x1) * ND);
    }
    u16x8 rg[2][8];                                // [half][corner*2+kk]
#pragma unroll
    for (int h = 0; h < 2; ++h)
#pragma unroll
        for (int c2 = 0; c2 < 4; ++c2) {
            rg[h][c2 * 2 + 0] = q[h][c2][0];
            rg[h][c2 * 2 + 1] = q[h][c2][4];
        }

    bf16x8 aF[2][2];                               // [half][kk]
#pragma unroll
    for (int h = 0; h < 2; ++h)
#pragma unroll
        for (int kk = 0; kk < 2; ++kk) {
            f32x4 bA = *(const f32x4*)&b1s[kk * 32 + 8 * g];
            f32x4 bB = *(const f32x4*)&b1s[kk * 32 + 8 * g + 4];
            u16x8 o;
#pragma unroll
            for (int j = 0; j < 8; ++j) {
                float v = w00[h] * bf2f(rg[h][0 + kk][j]) + w01[h] * bf2f(rg[h][2 + kk][j])
                        + w10[h] * bf2f(rg[h][4 + kk][j]) + w11[h] * bf2f(rg[h][6 + kk][j]);
                float bv = (j < 4) ? bA[j & 3] : bB[j & 3];
                o[j] = f2bf(fmaxf(v + bv, 0.f));
            }
            aF[h][kk] = __builtin_bit_cast(bf16x8, o);
        }

    f32x4 acc2[2][4];
#pragma unroll
    for (int mt = 0; mt < 2; ++mt)
#pragma unroll
        for (int nt = 0; nt < 4; ++nt) {
            const float bc = b2s[nt * 16 + mr];
            acc2[mt][nt] = (f32x4){bc, bc, bc, bc};
        }
#pragma unroll
    for (int kk = 0; kk < 2; ++kk)
#pragma unroll
        for (int nt = 0; nt < 4; ++nt) {
            bf16x8 bF = *(const bf16x8*)&w2s[((nt * 2 + kk) * 64 + lane) * 8];
            acc2[0][nt] = __builtin_amdgcn_mfma_f32_16x16x32_bf16(aF[0][kk], bF, acc2[0][nt], 0, 0, 0);
            acc2[1][nt] = __builtin_amdgcn_mfma_f32_16x16x32_bf16(aF[1][kk], bF, acc2[1][nt], 0, 0, 0);
        }

    // normalize rows (lane holds rows m0+mt*16+4g+r, cols nt*16+mr) + store
#pragma unroll
    for (int mt = 0; mt < 2; ++mt) {
        f32x4 ss = (f32x4){0.f, 0.f, 0.f, 0.f};
#pragma unroll
        for (int nt = 0; nt < 4; ++nt)
#pragma unroll
            for (int r = 0; r < 4; ++r) ss[r] += acc2[mt][nt][r] * acc2[mt][nt][r];
#pragma unroll
        for (int off = 1; off <= 8; off <<= 1) {
#pragma unroll
            for (int r = 0; r < 4; ++r) ss[r] += __shfl_xor(ss[r], off);
        }
#pragma unroll
        for (int r = 0; r < 4; ++r) {
            const float inv = 1.f / fmaxf(sqrtf(ss[r]), 1e-12f);
            const size_t ob = (size_t)(m0 + mt * 16 + 4 * g + r) * ND;
#pragma unroll
            for (int nt = 0; nt < 4; ++nt)
                out[ob + nt * 16 + mr] = acc2[mt][nt][r] * inv;
        }
    }
}

extern "C" void kernel_launch(void* const* d_in, const int* in_sizes, int n_in,
                              void* d_out, int out_size, void* d_ws, size_t ws_size,
                              hipStream_t stream) {
    const float* fm = (const float*)d_in[0];
    const float* pc = (const float*)d_in[1];
    const float* W1 = (const float*)d_in[2];
    const float* b1 = (const float*)d_in[3];
    const float* W2 = (const float*)d_in[4];
    const float* b2 = (const float*)d_in[5];
    float* out = (float*)d_out;
    unsigned short* U = (unsigned short*)d_ws;     // 131072 x 64 bf16 = 16 MB

    k_mlp1<<<NPX / 128, 256, 0, stream>>>(fm, W1, U);
    k_fused2<<<NPX / 128, 256, 0, stream>>>(U, pc, W2, b1, b2, out);
}